// Round 1
// baseline (1204.511 us; speedup 1.0000x reference)
//
#include <hip/hip_runtime.h>
#include <cstdint>

typedef short s16x8 __attribute__((ext_vector_type(8)));
typedef float f32x4 __attribute__((ext_vector_type(4)));
typedef unsigned short u16;

#define DEV static __device__ __forceinline__

DEV float bf2f(u16 b) {
  union { unsigned u; float f; } v; v.u = ((unsigned)b) << 16; return v.f;
}
DEV u16 f2bf(float f) {
  union { float f; unsigned u; } v; v.f = f;
  unsigned r = 0x7fffu + ((v.u >> 16) & 1u);   // RNE
  return (u16)((v.u + r) >> 16);
}

typedef __attribute__((address_space(3))) void lds_void_t;
typedef const __attribute__((address_space(1))) void glob_void_t;

DEV void async_copy16(const void* g, void* l) {
  __builtin_amdgcn_global_load_lds(
      (glob_void_t*)(uintptr_t)g,
      (lds_void_t*)(uint32_t)(uintptr_t)l,
      16, 0, 0);
}

// ---------------- fp32 -> bf16 convert (vectorized x4) ----------------
__global__ void cvt_f32_bf16(const float* __restrict__ in, u16* __restrict__ out, int n4) {
  int i = blockIdx.x * 256 + threadIdx.x;
  if (i < n4) {
    const float4 v = reinterpret_cast<const float4*>(in)[i];
    ushort4 o;
    o.x = f2bf(v.x); o.y = f2bf(v.y); o.z = f2bf(v.z); o.w = f2bf(v.w);
    reinterpret_cast<ushort4*>(out)[i] = o;
  }
}

// ---------------- NT GEMM: C[m,n] = sum_k A[m,k]*B[n,k] ----------------
// A: MxK bf16 row-major, B: NxK bf16 row-major. BM=BN=128, BK=32.
// 256 threads = 4 waves; wave (wr,wc) owns a 64x64 quadrant = 4x4 MFMA tiles.
// LDS staged via global_load_lds (16B/lane); k-chunk XOR-swizzled by (row>>1)&3
// so ds_read_b128 fragment reads are 2-way (free) instead of 8-way conflicted.
template <bool OUT_BF16>
__global__ __launch_bounds__(256, 2)
void gemm_nt(const u16* __restrict__ A, const u16* __restrict__ B,
             void* __restrict__ C, int M, int N, int K) {
  __shared__ u16 As[128 * 32];
  __shared__ u16 Bs[128 * 32];
  const int tid  = threadIdx.x;
  const int lane = tid & 63;
  const int wave = tid >> 6;
  const int wr = wave >> 1, wc = wave & 1;
  const int l15 = lane & 15, quad = lane >> 4;
  const int bm = blockIdx.x, bn = blockIdx.y;

  const int srow   = lane >> 2;                       // staging row within 16-row group
  const int schunk = (lane & 3) ^ ((srow >> 1) & 3);  // swizzled global k-chunk
  const int fsw    = (l15 >> 1) & 3;                  // fragment-read swizzle

  f32x4 acc[4][4];
  const f32x4 zero4 = {0.f, 0.f, 0.f, 0.f};
#pragma unroll
  for (int i = 0; i < 4; ++i)
#pragma unroll
    for (int j = 0; j < 4; ++j) acc[i][j] = zero4;

  const size_t Abase = (size_t)(bm * 128) * K;
  const size_t Bbase = (size_t)(bn * 128) * K;

  for (int kt = 0; kt < K; kt += 32) {
#pragma unroll
    for (int c = 0; c < 2; ++c) {
      const int grp = wave * 2 + c;          // 0..7 -> 16 rows each
      const int row = grp * 16 + srow;
      const u16* gA = A + Abase + (size_t)row * K + kt + schunk * 8;
      const u16* gB = B + Bbase + (size_t)row * K + kt + schunk * 8;
      async_copy16(gA, As + grp * 512 + lane * 8);
      async_copy16(gB, Bs + grp * 512 + lane * 8);
    }
    __syncthreads();

    s16x8 af[4], bf[4];
#pragma unroll
    for (int mi = 0; mi < 4; ++mi) {
      const int row = wr * 64 + mi * 16 + l15;
      af[mi] = *(const s16x8*)(As + row * 32 + (quad ^ fsw) * 8);
    }
#pragma unroll
    for (int ni = 0; ni < 4; ++ni) {
      const int row = wc * 64 + ni * 16 + l15;
      bf[ni] = *(const s16x8*)(Bs + row * 32 + (quad ^ fsw) * 8);
    }
#pragma unroll
    for (int mi = 0; mi < 4; ++mi)
#pragma unroll
      for (int ni = 0; ni < 4; ++ni)
        acc[mi][ni] = __builtin_amdgcn_mfma_f32_16x16x32_bf16(af[mi], bf[ni], acc[mi][ni], 0, 0, 0);
    __syncthreads();
  }

  // epilogue: C/D layout col=lane&15, row=quad*4+reg
#pragma unroll
  for (int mi = 0; mi < 4; ++mi) {
#pragma unroll
    for (int ni = 0; ni < 4; ++ni) {
      const int gm0 = bm * 128 + wr * 64 + mi * 16 + quad * 4;
      const int gn  = bn * 128 + wc * 64 + ni * 16 + l15;
#pragma unroll
      for (int r = 0; r < 4; ++r) {
        const size_t idx = (size_t)(gm0 + r) * N + gn;
        if (OUT_BF16) ((u16*)C)[idx] = f2bf(acc[mi][ni][r]);
        else          ((float*)C)[idx] = acc[mi][ni][r];
      }
    }
  }
}

// ---------------- RoPE + split + layout change ----------------
// qkv: [4096 tokens][9216] bf16.  Writes:
//   Q  [bh][l][96] bf16, scale 96^-0.5 folded in
//   K  [bh][l][96] bf16
//   Vt [bh][96][l] bf16  (transposed so PV B-fragments read contiguous 16B)
__global__ void rope_split(const u16* __restrict__ qkv, u16* __restrict__ Q,
                           u16* __restrict__ Kb, u16* __restrict__ Vt) {
  const int tok = blockIdx.x;          // 0..4095
  const int b = tok >> 11, l = tok & 2047;
  const float pos = (float)l;
  const float SF = 1.1902380714238083f;          // sqrt(1 + log(32)/log(4096))
  const float QSCALE = 0.10206207261596575f;     // 96^-0.5
  const size_t base = (size_t)tok * 9216;
  for (int i = threadIdx.x; i < 3072; i += 256) {
    const int h = i / 96, d = i - h * 96;
    const float qv = bf2f(qkv[base + i]);
    const float kv = bf2f(qkv[base + 3072 + i]);
    const float vv = bf2f(qkv[base + 6144 + i]);
    const int dp    = (d < 48) ? d + 48 : d - 48;
    const float sgn = (d < 48) ? -1.0f : 1.0f;
    const float qp = bf2f(qkv[base + h * 96 + dp]) * sgn;
    const float kp = bf2f(qkv[base + 3072 + h * 96 + dp]) * sgn;
    const int fi = (d < 48) ? d : d - 48;
    // inv_freq = 10000^(-fi/48) = 2^(-log2(10000) * fi/48)
    const float inv = exp2f(-13.287712379549449f * ((float)fi * (1.0f / 48.0f)));
    const float ang = pos * inv;
    float s, c;
    sincosf(ang, &s, &c);
    c *= SF; s *= SF;
    const float qo = qv * c + qp * s;
    const float ko = kv * c + kp * s;
    const int bh = b * 32 + h;
    Q [((size_t)bh * 2048 + l) * 96 + d] = f2bf(qo * QSCALE);
    Kb[((size_t)bh * 2048 + l) * 96 + d] = f2bf(ko);
    Vt[((size_t)bh * 96 + d) * 2048 + l] = f2bf(vv);
  }
}

// ---------------- flash attention (causal) ----------------
// grid (32 qblocks, 64 bh), 256 thr = 4 waves. Wave w: q rows qb*64+w*16 .. +16.
// 32-key blocks: QK^T = 3 chained mfma per 16-key subtile; online softmax with
// 16-lane shfl reductions; P -> LDS (padded) -> A-fragment; PV = 6 mfma.
__global__ __launch_bounds__(256, 2)
void attn(const u16* __restrict__ Q, const u16* __restrict__ Kb,
          const u16* __restrict__ Vt, u16* __restrict__ ctx) {
  const int qb = blockIdx.x;   // 0..31
  const int bh = blockIdx.y;   // 0..63
  const int tid = threadIdx.x, lane = tid & 63, wave = tid >> 6;
  const int l15 = lane & 15, quad = lane >> 4;
  __shared__ u16 Pl[4][16][40];          // per-wave P tile, rows padded to 80B

  const size_t hbase = (size_t)bh * 2048 * 96;
  const int q0 = qb * 64 + wave * 16;

  s16x8 aq[3];
#pragma unroll
  for (int c = 0; c < 3; ++c)
    aq[c] = *(const s16x8*)(Q + hbase + (size_t)(q0 + l15) * 96 + c * 32 + quad * 8);

  float m_[4] = {-1e30f, -1e30f, -1e30f, -1e30f};
  float l_[4] = {0.f, 0.f, 0.f, 0.f};
  f32x4 o[6];
  const f32x4 zero4 = {0.f, 0.f, 0.f, 0.f};
#pragma unroll
  for (int d = 0; d < 6; ++d) o[d] = zero4;

  const int nkb = (qb + 1) * 2;          // 32-key blocks up to WG causal limit
  for (int kb = 0; kb < nkb; ++kb) {
    const int k0 = kb * 32;
    f32x4 s[2];
#pragma unroll
    for (int sub = 0; sub < 2; ++sub) {
      const size_t kro = hbase + (size_t)(k0 + sub * 16 + l15) * 96 + quad * 8;
      const s16x8 b0 = *(const s16x8*)(Kb + kro);
      const s16x8 b1 = *(const s16x8*)(Kb + kro + 32);
      const s16x8 b2 = *(const s16x8*)(Kb + kro + 64);
      f32x4 t = __builtin_amdgcn_mfma_f32_16x16x32_bf16(aq[0], b0, zero4, 0, 0, 0);
      t = __builtin_amdgcn_mfma_f32_16x16x32_bf16(aq[1], b1, t, 0, 0, 0);
      t = __builtin_amdgcn_mfma_f32_16x16x32_bf16(aq[2], b2, t, 0, 0, 0);
      s[sub] = t;
    }
    // causal mask: C-layout row = quad*4+r, col = l15
#pragma unroll
    for (int sub = 0; sub < 2; ++sub)
#pragma unroll
      for (int r = 0; r < 4; ++r) {
        const int row = q0 + quad * 4 + r;
        const int col = k0 + sub * 16 + l15;
        if (col > row) s[sub][r] = -1e30f;
      }
    // online softmax
    float alpha[4];
#pragma unroll
    for (int r = 0; r < 4; ++r) {
      float mx = fmaxf(s[0][r], s[1][r]);
#pragma unroll
      for (int off = 8; off >= 1; off >>= 1) mx = fmaxf(mx, __shfl_xor(mx, off));
      const float mn = fmaxf(m_[r], mx);
      alpha[r] = __expf(m_[r] - mn);
      const float p0 = __expf(s[0][r] - mn);
      const float p1 = __expf(s[1][r] - mn);
      s[0][r] = p0; s[1][r] = p1;
      float rs = p0 + p1;
#pragma unroll
      for (int off = 8; off >= 1; off >>= 1) rs += __shfl_xor(rs, off);
      l_[r] = l_[r] * alpha[r] + rs;
      m_[r] = mn;
    }
#pragma unroll
    for (int d = 0; d < 6; ++d)
#pragma unroll
      for (int r = 0; r < 4; ++r) o[d][r] *= alpha[r];

    // P: C-layout -> LDS -> A-layout
#pragma unroll
    for (int sub = 0; sub < 2; ++sub)
#pragma unroll
      for (int r = 0; r < 4; ++r)
        Pl[wave][quad * 4 + r][sub * 16 + l15] = f2bf(s[sub][r]);
    __syncthreads();
    const s16x8 ap = *(const s16x8*)(&Pl[wave][l15][quad * 8]);
#pragma unroll
    for (int d = 0; d < 6; ++d) {
      const s16x8 bv = *(const s16x8*)(Vt + ((size_t)bh * 96 + d * 16 + l15) * 2048 + k0 + quad * 8);
      o[d] = __builtin_amdgcn_mfma_f32_16x16x32_bf16(ap, bv, o[d], 0, 0, 0);
    }
    __syncthreads();
  }

  // write ctx[b, q, h*96 + d] bf16
  const int b = bh >> 5, h = bh & 31;
  float invl[4];
#pragma unroll
  for (int r = 0; r < 4; ++r) invl[r] = 1.0f / l_[r];
#pragma unroll
  for (int d = 0; d < 6; ++d)
#pragma unroll
    for (int r = 0; r < 4; ++r) {
      const int row = q0 + quad * 4 + r;
      ctx[((size_t)(b * 2048 + row)) * 3072 + h * 96 + d * 16 + l15] = f2bf(o[d][r] * invl[r]);
    }
}

// ---------------- launch ----------------
extern "C" void kernel_launch(void* const* d_in, const int* in_sizes, int n_in,
                              void* d_out, int out_size, void* d_ws, size_t ws_size,
                              hipStream_t stream) {
  const float* x    = (const float*)d_in[0];   // [2,2048,3072]
  const float* Wqkv = (const float*)d_in[1];   // [9216,3072]
  const float* Wo   = (const float*)d_in[2];   // [3072,3072]
  float* out = (float*)d_out;                  // [2,2048,3072] fp32

  char* ws = (char*)d_ws;
  // layout (bytes):
  u16* wq_b  = (u16*)(ws);                  // Wqkv bf16: 28,311,552 el -> 56,623,104 B
  u16* wo_b  = (u16*)(ws + 56623104);       // Wo   bf16:  9,437,184 el -> 18,874,368 B
  u16* x_b   = (u16*)(ws + 75497472);       // x    bf16: 12,582,912 el -> 25,165,824 B
  u16* qkv_b = (u16*)(ws + 100663296);      // qkv  bf16: 37,748,736 el -> 75,497,472 B
  u16* K_b   = (u16*)(ws + 176160768);      // K    bf16: 12,582,912 el -> 25,165,824 B
  u16* Vt_b  = (u16*)(ws + 201326592);      // Vt   bf16: 12,582,912 el -> 25,165,824 B
  u16* Q_b   = x_b;                         // alias: x dead after GEMM1
  u16* ctx_b = qkv_b;                       // alias: qkv dead after rope_split

  cvt_f32_bf16<<<27648, 256, 0, stream>>>(Wqkv, wq_b, 28311552 / 4);
  cvt_f32_bf16<<<9216,  256, 0, stream>>>(Wo,   wo_b,  9437184 / 4);
  cvt_f32_bf16<<<12288, 256, 0, stream>>>(x,    x_b,  12582912 / 4);

  // qkv = x @ Wqkv^T   [4096 x 9216], K=3072
  gemm_nt<true><<<dim3(32, 72), 256, 0, stream>>>(x_b, wq_b, (void*)qkv_b, 4096, 9216, 3072);

  rope_split<<<4096, 256, 0, stream>>>(qkv_b, Q_b, K_b, Vt_b);

  attn<<<dim3(32, 64), 256, 0, stream>>>(Q_b, K_b, Vt_b, ctx_b);

  // out = ctx @ Wo^T   [4096 x 3072], K=3072, fp32 out
  gemm_nt<false><<<dim3(32, 24), 256, 0, stream>>>(ctx_b, wo_b, (void*)out, 4096, 3072, 3072);
}

// Round 2
// 1197.960 us; speedup vs baseline: 1.0055x; 1.0055x over previous
//
#include <hip/hip_runtime.h>
#include <cstdint>

typedef short s16x8 __attribute__((ext_vector_type(8)));
typedef float f32x4 __attribute__((ext_vector_type(4)));
typedef unsigned short u16;

#define DEV static __device__ __forceinline__

DEV float bf2f(u16 b) {
  union { unsigned u; float f; } v; v.u = ((unsigned)b) << 16; return v.f;
}
DEV u16 f2bf(float f) {
  union { float f; unsigned u; } v; v.f = f;
  unsigned r = 0x7fffu + ((v.u >> 16) & 1u);   // RNE
  return (u16)((v.u + r) >> 16);
}

typedef __attribute__((address_space(3))) void lds_void_t;
typedef const __attribute__((address_space(1))) void glob_void_t;

DEV void async_copy16(const void* g, void* l) {
  __builtin_amdgcn_global_load_lds(
      (glob_void_t*)(uintptr_t)g,
      (lds_void_t*)(uint32_t)(uintptr_t)l,
      16, 0, 0);
}

// ---------------- fp32 -> bf16 convert (vectorized x4) ----------------
__global__ void cvt_f32_bf16(const float* __restrict__ in, u16* __restrict__ out, int n4) {
  int i = blockIdx.x * 256 + threadIdx.x;
  if (i < n4) {
    const float4 v = reinterpret_cast<const float4*>(in)[i];
    ushort4 o;
    o.x = f2bf(v.x); o.y = f2bf(v.y); o.z = f2bf(v.z); o.w = f2bf(v.w);
    reinterpret_cast<ushort4*>(out)[i] = o;
  }
}

// ---------------- NT GEMM: C[m,n] = sum_k A[m,k]*B[n,k] ----------------
// (unchanged from R1 — isolating the attn rewrite this round)
template <bool OUT_BF16>
__global__ __launch_bounds__(256, 2)
void gemm_nt(const u16* __restrict__ A, const u16* __restrict__ B,
             void* __restrict__ C, int M, int N, int K) {
  __shared__ u16 As[128 * 32];
  __shared__ u16 Bs[128 * 32];
  const int tid  = threadIdx.x;
  const int lane = tid & 63;
  const int wave = tid >> 6;
  const int wr = wave >> 1, wc = wave & 1;
  const int l15 = lane & 15, quad = lane >> 4;
  const int bm = blockIdx.x, bn = blockIdx.y;

  const int srow   = lane >> 2;
  const int schunk = (lane & 3) ^ ((srow >> 1) & 3);
  const int fsw    = (l15 >> 1) & 3;

  f32x4 acc[4][4];
  const f32x4 zero4 = {0.f, 0.f, 0.f, 0.f};
#pragma unroll
  for (int i = 0; i < 4; ++i)
#pragma unroll
    for (int j = 0; j < 4; ++j) acc[i][j] = zero4;

  const size_t Abase = (size_t)(bm * 128) * K;
  const size_t Bbase = (size_t)(bn * 128) * K;

  for (int kt = 0; kt < K; kt += 32) {
#pragma unroll
    for (int c = 0; c < 2; ++c) {
      const int grp = wave * 2 + c;
      const int row = grp * 16 + srow;
      const u16* gA = A + Abase + (size_t)row * K + kt + schunk * 8;
      const u16* gB = B + Bbase + (size_t)row * K + kt + schunk * 8;
      async_copy16(gA, As + grp * 512 + lane * 8);
      async_copy16(gB, Bs + grp * 512 + lane * 8);
    }
    __syncthreads();

    s16x8 af[4], bf[4];
#pragma unroll
    for (int mi = 0; mi < 4; ++mi) {
      const int row = wr * 64 + mi * 16 + l15;
      af[mi] = *(const s16x8*)(As + row * 32 + (quad ^ fsw) * 8);
    }
#pragma unroll
    for (int ni = 0; ni < 4; ++ni) {
      const int row = wc * 64 + ni * 16 + l15;
      bf[ni] = *(const s16x8*)(Bs + row * 32 + (quad ^ fsw) * 8);
    }
#pragma unroll
    for (int mi = 0; mi < 4; ++mi)
#pragma unroll
      for (int ni = 0; ni < 4; ++ni)
        acc[mi][ni] = __builtin_amdgcn_mfma_f32_16x16x32_bf16(af[mi], bf[ni], acc[mi][ni], 0, 0, 0);
    __syncthreads();
  }

#pragma unroll
  for (int mi = 0; mi < 4; ++mi) {
#pragma unroll
    for (int ni = 0; ni < 4; ++ni) {
      const int gm0 = bm * 128 + wr * 64 + mi * 16 + quad * 4;
      const int gn  = bn * 128 + wc * 64 + ni * 16 + l15;
#pragma unroll
      for (int r = 0; r < 4; ++r) {
        const size_t idx = (size_t)(gm0 + r) * N + gn;
        if (OUT_BF16) ((u16*)C)[idx] = f2bf(acc[mi][ni][r]);
        else          ((float*)C)[idx] = acc[mi][ni][r];
      }
    }
  }
}

// ---------------- RoPE + split + layout change (vectorized x4) ----------------
__global__ void rope_split(const u16* __restrict__ qkv, u16* __restrict__ Q,
                           u16* __restrict__ Kb, u16* __restrict__ Vt) {
  const int tok = blockIdx.x;          // 0..4095
  const int b = tok >> 11, l = tok & 2047;
  const float pos = (float)l;
  const float SF = 1.1902380714238083f;          // sqrt(1 + log(32)/log(4096))
  const float QSCALE = 0.10206207261596575f;     // 96^-0.5
  const size_t base = (size_t)tok * 9216;
  for (int i = threadIdx.x; i < 768; i += 256) {
    const int g = i * 4;
    const int h = g / 96, d0 = g - h * 96;       // d0 multiple of 4; halves aligned
    const ushort4 qv4 = *(const ushort4*)(qkv + base + g);
    const ushort4 kv4 = *(const ushort4*)(qkv + base + 3072 + g);
    const ushort4 vv4 = *(const ushort4*)(qkv + base + 6144 + g);
    const int dp0    = (d0 < 48) ? d0 + 48 : d0 - 48;
    const float sgn  = (d0 < 48) ? -1.0f : 1.0f;
    const ushort4 qp4 = *(const ushort4*)(qkv + base + h * 96 + dp0);
    const ushort4 kp4 = *(const ushort4*)(qkv + base + 3072 + h * 96 + dp0);
    const int fi0 = (d0 < 48) ? d0 : d0 - 48;
    const int bh = b * 32 + h;
    ushort4 qo, ko;
    const u16* qvp = (const u16*)&qv4; const u16* kvp = (const u16*)&kv4;
    const u16* qpp = (const u16*)&qp4; const u16* kpp = (const u16*)&kp4;
    const u16* vvp = (const u16*)&vv4;
    u16* qop = (u16*)&qo; u16* kop = (u16*)&ko;
#pragma unroll
    for (int e = 0; e < 4; ++e) {
      const float inv = exp2f(-13.287712379549449f * ((float)(fi0 + e) * (1.0f / 48.0f)));
      const float ang = pos * inv;
      float s, c;
      sincosf(ang, &s, &c);
      c *= SF; s *= SF;
      const float qout = bf2f(qvp[e]) * c + bf2f(qpp[e]) * sgn * s;
      const float kout = bf2f(kvp[e]) * c + bf2f(kpp[e]) * sgn * s;
      qop[e] = f2bf(qout * QSCALE);
      kop[e] = f2bf(kout);
      Vt[((size_t)bh * 96 + d0 + e) * 2048 + l] = vvp[e];
    }
    *(ushort4*)(Q  + ((size_t)bh * 2048 + l) * 96 + d0) = qo;
    *(ushort4*)(Kb + ((size_t)bh * 2048 + l) * 96 + d0) = ko;
  }
}

// ---------------- flash attention (causal), barrier-free ----------------
// grid (32 qblocks, 64 bh), 256 thr = 4 waves; wave w owns q rows qb*64+w*16..+15.
// 64-key blocks: QK^T = 4 subtiles x 3 chained mfma; online softmax (16-lane shfl);
// P -> per-wave padded LDS (no __syncthreads: intra-wave lgkmcnt ordering only);
// PV = 2 k-chunks x 6 mfma. Diagonal block skips fully-masked subtiles/chunks.
// Heavy q-blocks launch first (qb = 31 - blockIdx.x) to kill the causal tail.
__global__ __launch_bounds__(256, 3)
void attn(const u16* __restrict__ Q, const u16* __restrict__ Kb,
          const u16* __restrict__ Vt, u16* __restrict__ ctx) {
  const int qb = 31 - blockIdx.x;   // heavy blocks first
  const int bh = blockIdx.y;        // 0..63
  const int tid = threadIdx.x, lane = tid & 63, wave = tid >> 6;
  const int l15 = lane & 15, quad = lane >> 4;
  __shared__ alignas(16) u16 Pl[4][16][80];   // per-wave P tile, rows padded to 160B

  const size_t hbase = (size_t)bh * 2048 * 96;
  const int q0 = qb * 64 + wave * 16;

  s16x8 aq[3];
#pragma unroll
  for (int c = 0; c < 3; ++c)
    aq[c] = *(const s16x8*)(Q + hbase + (size_t)(q0 + l15) * 96 + c * 32 + quad * 8);

  float m_[4] = {-1e30f, -1e30f, -1e30f, -1e30f};
  float l_[4] = {0.f, 0.f, 0.f, 0.f};
  f32x4 o[6];
  const f32x4 zero4 = {0.f, 0.f, 0.f, 0.f};
#pragma unroll
  for (int d = 0; d < 6; ++d) o[d] = zero4;

  for (int kb = 0; kb <= qb; ++kb) {
    const int k0 = kb * 64;
    const bool last = (kb == qb);
    const int nsub   = last ? (wave + 1) : 4;        // QK^T subtiles needed
    const int nchunk = last ? ((wave >> 1) + 1) : 2; // PV 32-key chunks needed
    const int nsw    = nchunk * 2;                   // P subtiles that must land in LDS

    f32x4 s[4];
#pragma unroll
    for (int sub = 0; sub < 4; ++sub) {
      if (sub < nsub) {
        const size_t kro = hbase + (size_t)(k0 + sub * 16 + l15) * 96 + quad * 8;
        const s16x8 b0 = *(const s16x8*)(Kb + kro);
        const s16x8 b1 = *(const s16x8*)(Kb + kro + 32);
        const s16x8 b2 = *(const s16x8*)(Kb + kro + 64);
        f32x4 t = __builtin_amdgcn_mfma_f32_16x16x32_bf16(aq[0], b0, zero4, 0, 0, 0);
        t = __builtin_amdgcn_mfma_f32_16x16x32_bf16(aq[1], b1, t, 0, 0, 0);
        t = __builtin_amdgcn_mfma_f32_16x16x32_bf16(aq[2], b2, t, 0, 0, 0);
        s[sub] = t;
      } else {
        s[sub] = (f32x4){-1e30f, -1e30f, -1e30f, -1e30f};
      }
    }

    // causal mask only ever bites in the diagonal block
    if (last) {
#pragma unroll
      for (int sub = 0; sub < 4; ++sub)
#pragma unroll
        for (int r = 0; r < 4; ++r) {
          const int row = q0 + quad * 4 + r;
          const int col = k0 + sub * 16 + l15;
          if (col > row) s[sub][r] = -1e30f;
        }
    }

    // online softmax (rows spread over 16 lanes; offsets 1..8 stay in-group)
    float alpha[4];
#pragma unroll
    for (int r = 0; r < 4; ++r) {
      float mx = fmaxf(fmaxf(s[0][r], s[1][r]), fmaxf(s[2][r], s[3][r]));
#pragma unroll
      for (int off = 8; off >= 1; off >>= 1) mx = fmaxf(mx, __shfl_xor(mx, off));
      const float mn = fmaxf(m_[r], mx);
      alpha[r] = __expf(m_[r] - mn);
      const float p0 = __expf(s[0][r] - mn);
      const float p1 = __expf(s[1][r] - mn);
      const float p2 = __expf(s[2][r] - mn);
      const float p3 = __expf(s[3][r] - mn);
      s[0][r] = p0; s[1][r] = p1; s[2][r] = p2; s[3][r] = p3;
      float rs = (p0 + p1) + (p2 + p3);
#pragma unroll
      for (int off = 8; off >= 1; off >>= 1) rs += __shfl_xor(rs, off);
      l_[r] = l_[r] * alpha[r] + rs;
      m_[r] = mn;
    }
#pragma unroll
    for (int d = 0; d < 6; ++d)
#pragma unroll
      for (int r = 0; r < 4; ++r) o[d][r] *= alpha[r];

    // P: C-layout -> per-wave LDS (row stride 160B: conflict-free b16 writes)
#pragma unroll
    for (int sub = 0; sub < 4; ++sub) {
      if (sub < nsw) {
#pragma unroll
        for (int r = 0; r < 4; ++r)
          Pl[wave][quad * 4 + r][sub * 16 + l15] = f2bf(s[sub][r]);
      }
    }

    // PV: A-fragment from LDS (intra-wave dependency; compiler inserts lgkmcnt)
#pragma unroll
    for (int c = 0; c < 2; ++c) {
      if (c < nchunk) {
        const s16x8 ap = *(const s16x8*)(&Pl[wave][l15][c * 32 + quad * 8]);
#pragma unroll
        for (int d = 0; d < 6; ++d) {
          const s16x8 bv = *(const s16x8*)(Vt + ((size_t)bh * 96 + d * 16 + l15) * 2048
                                              + k0 + c * 32 + quad * 8);
          o[d] = __builtin_amdgcn_mfma_f32_16x16x32_bf16(ap, bv, o[d], 0, 0, 0);
        }
      }
    }
  }

  // write ctx[b, q, h*96 + d] bf16
  const int b = bh >> 5, h = bh & 31;
  float invl[4];
#pragma unroll
  for (int r = 0; r < 4; ++r) invl[r] = 1.0f / l_[r];
#pragma unroll
  for (int d = 0; d < 6; ++d)
#pragma unroll
    for (int r = 0; r < 4; ++r) {
      const int row = q0 + quad * 4 + r;
      ctx[((size_t)(b * 2048 + row)) * 3072 + h * 96 + d * 16 + l15] = f2bf(o[d][r] * invl[r]);
    }
}

// ---------------- launch ----------------
extern "C" void kernel_launch(void* const* d_in, const int* in_sizes, int n_in,
                              void* d_out, int out_size, void* d_ws, size_t ws_size,
                              hipStream_t stream) {
  const float* x    = (const float*)d_in[0];   // [2,2048,3072]
  const float* Wqkv = (const float*)d_in[1];   // [9216,3072]
  const float* Wo   = (const float*)d_in[2];   // [3072,3072]
  float* out = (float*)d_out;                  // [2,2048,3072] fp32

  char* ws = (char*)d_ws;
  u16* wq_b  = (u16*)(ws);                  // 56,623,104 B
  u16* wo_b  = (u16*)(ws + 56623104);       // 18,874,368 B
  u16* x_b   = (u16*)(ws + 75497472);       // 25,165,824 B
  u16* qkv_b = (u16*)(ws + 100663296);      // 75,497,472 B
  u16* K_b   = (u16*)(ws + 176160768);      // 25,165,824 B
  u16* Vt_b  = (u16*)(ws + 201326592);      // 25,165,824 B
  u16* Q_b   = x_b;                         // alias: x dead after GEMM1
  u16* ctx_b = qkv_b;                       // alias: qkv dead after rope_split

  cvt_f32_bf16<<<27648, 256, 0, stream>>>(Wqkv, wq_b, 28311552 / 4);
  cvt_f32_bf16<<<9216,  256, 0, stream>>>(Wo,   wo_b,  9437184 / 4);
  cvt_f32_bf16<<<12288, 256, 0, stream>>>(x,    x_b,  12582912 / 4);

  // qkv = x @ Wqkv^T   [4096 x 9216], K=3072
  gemm_nt<true><<<dim3(32, 72), 256, 0, stream>>>(x_b, wq_b, (void*)qkv_b, 4096, 9216, 3072);

  rope_split<<<4096, 256, 0, stream>>>(qkv_b, Q_b, K_b, Vt_b);

  attn<<<dim3(32, 64), 256, 0, stream>>>(Q_b, K_b, Vt_b, ctx_b);

  // out = ctx @ Wo^T   [4096 x 3072], K=3072, fp32 out
  gemm_nt<false><<<dim3(32, 24), 256, 0, stream>>>(ctx_b, wo_b, (void*)out, 4096, 3072, 3072);
}